// Round 2
// baseline (216.065 us; speedup 1.0000x reference)
//
#include <hip/hip_runtime.h>

// MHAttention B=8 T=2048 C=512 H=512, causal, fp32 in/out.
// Pipeline: cast(fp32->fp16) -> fused QKV GEMM (writes Q,K row-major, V transposed)
//           -> flash attention (paired q-tiles for causal load balance).
// fp16 (not bf16): 4x lower rounding error at identical MFMA rate; all
// intermediates (|x|,|q|,|k|,|v|<~6, P in [0,1]) fit fp16 range.

using short8 = __attribute__((ext_vector_type(8))) short;
using half8  = __attribute__((ext_vector_type(8))) _Float16;
using f32x4  = __attribute__((ext_vector_type(4))) float;

#define B_    8
#define T_    2048
#define C_    512
#define SCALE_ 0.044194173824159216f   // 512^-0.5

// dynamic LDS layout for flash kernel
#define LDS_V_OFF   65536
#define LDS_SP_OFF  131072
#define LDS_P_OFF   140288
#define LDS_RM_OFF  142848
#define LDS_RL_OFF  142976
#define LDS_AL_OFF  143104
#define SMEM_BYTES  143232

__device__ __forceinline__ void gload_lds16(const void* g, void* l) {
  __builtin_amdgcn_global_load_lds(
      (const __attribute__((address_space(1))) unsigned int*)g,
      (__attribute__((address_space(3))) unsigned int*)l, 16, 0, 0);
}

__device__ __forceinline__ unsigned short f2h(float f) {  // RNE f32->f16 bits
  _Float16 h = (_Float16)f;
  return *(unsigned short*)&h;
}

// cross-wave LDS barrier WITHOUT draining vmcnt (keeps global_load_lds prefetch in flight)
__device__ __forceinline__ void barrier_lgkm() {
  asm volatile("s_waitcnt lgkmcnt(0)" ::: "memory");
  __builtin_amdgcn_s_barrier();
  asm volatile("" ::: "memory");
}

// ---------------------------------------------------------------- cast kernel
__global__ __launch_bounds__(256) void cast_kernel(
    const float* __restrict__ x, const float* __restrict__ wq,
    const float* __restrict__ wk, const float* __restrict__ wv,
    unsigned short* __restrict__ xb, unsigned short* __restrict__ wcat) {
  size_t i4 = (size_t)blockIdx.x * 256 + threadIdx.x;   // one float4 per thread
  const size_t NX4 = (size_t)(B_ * T_ * C_) / 4;        // 2097152
  const float* src; unsigned short* dst; size_t off4;
  if (i4 < NX4) { src = x; dst = xb; off4 = i4; }
  else {
    size_t w4 = i4 - NX4;                 // < 196608
    size_t mat = w4 >> 16;                // 65536 float4 per 512x512 matrix
    off4 = w4 & 65535;
    src = (mat == 0) ? wq : (mat == 1) ? wk : wv;
    dst = wcat + (mat << 18);
  }
  float4 v = ((const float4*)src)[off4];
  unsigned long long pk = (unsigned long long)f2h(v.x)
                        | ((unsigned long long)f2h(v.y) << 16)
                        | ((unsigned long long)f2h(v.z) << 32)
                        | ((unsigned long long)f2h(v.w) << 48);
  *(unsigned long long*)(dst + off4 * 4) = pk;
}

// ---------------------------------------------------------------- QKV GEMM
// C[m][n] = sum_k xb[m][k] * wcat[n][k],  M=16384, N=1536, K=512.
// 128x128 tile, BK=64, 4 waves (2x2), 16x16x32 f16 MFMA, double-buffered LDS.
// LDS tiles [128 rows][64 k] f16, 128B rows; XOR swizzle: granule' = granule ^ (row&7).
__device__ __forceinline__ void gemm_stage(
    const unsigned short* __restrict__ xb, const unsigned short* __restrict__ wcat,
    char* smem, int buf, int mbase, int nbase, int kt, int wv, int lane, int srcg) {
  char* base = smem + buf * 32768;
  const int kbase = kt * 64;
  if (wv < 2) {
    #pragma unroll
    for (int i = 0; i < 8; ++i) {
      const int blk = wv * 8 + i;                 // 16 x 1KB blocks (8 rows each)
      const int row = blk * 8 + (lane >> 3);
      gload_lds16(xb + (size_t)(mbase + row) * 512 + kbase + srcg, base + blk * 1024);
    }
  } else {
    #pragma unroll
    for (int i = 0; i < 8; ++i) {
      const int blk = (wv - 2) * 8 + i;
      const int row = blk * 8 + (lane >> 3);
      gload_lds16(wcat + (size_t)(nbase + row) * 512 + kbase + srcg, base + 16384 + blk * 1024);
    }
  }
}

__global__ __launch_bounds__(256, 2) void gemm_qkv(
    const unsigned short* __restrict__ xb, const unsigned short* __restrict__ wcat,
    unsigned short* __restrict__ Qb, unsigned short* __restrict__ Kb,
    unsigned short* __restrict__ Vtb) {
  __shared__ char smem[65536];
  const int tid = threadIdx.x, lane = tid & 63, wv = tid >> 6;
  const int wr = wv >> 1, wc = wv & 1;
  const int l15 = lane & 15, l4 = lane >> 4;
  const int mbase = blockIdx.y * 128;
  const int nbase = blockIdx.x * 128;
  // staging source swizzle: LDS granule g of row r holds global granule g ^ (r&7)
  const int srcg = (((lane & 7) ^ ((lane >> 3) & 7))) * 8;

  f32x4 acc[4][4];
  #pragma unroll
  for (int i = 0; i < 4; ++i)
    #pragma unroll
    for (int j = 0; j < 4; ++j) acc[i][j] = (f32x4){0.f, 0.f, 0.f, 0.f};

  gemm_stage(xb, wcat, smem, 0, mbase, nbase, 0, wv, lane, srcg);
  for (int kt = 0; kt < 8; ++kt) {
    __syncthreads();                               // staged tile ready (vmcnt drained)
    if (kt < 7) gemm_stage(xb, wcat, smem, (kt + 1) & 1, mbase, nbase, kt + 1, wv, lane, srcg);
    const char* base = smem + (kt & 1) * 32768;
    #pragma unroll
    for (int ks = 0; ks < 2; ++ks) {
      half8 a[4], b8[4];
      #pragma unroll
      for (int rt = 0; rt < 4; ++rt) {
        const int row = wr * 64 + rt * 16 + l15;
        const int G = (ks * 4 + l4) ^ (row & 7);
        a[rt] = *(const half8*)(base + row * 128 + G * 16);
      }
      #pragma unroll
      for (int ct = 0; ct < 4; ++ct) {
        const int row = wc * 64 + ct * 16 + l15;
        const int G = (ks * 4 + l4) ^ (row & 7);
        b8[ct] = *(const half8*)(base + 16384 + row * 128 + G * 16);
      }
      #pragma unroll
      for (int rt = 0; rt < 4; ++rt)
        #pragma unroll
        for (int ct = 0; ct < 4; ++ct)
          acc[rt][ct] = __builtin_amdgcn_mfma_f32_16x16x32_f16(a[rt], b8[ct], acc[rt][ct], 0, 0, 0);
    }
  }

  // epilogue: C/D layout col=lane&15, row=(lane>>4)*4+j (m89-verified)
  const int mat = nbase >> 9;          // 0=Q, 1=K, 2=V
  const int nloc = nbase & 511;
  if (mat < 2) {
    unsigned short* O = (mat == 0) ? Qb : Kb;
    #pragma unroll
    for (int rt = 0; rt < 4; ++rt)
      #pragma unroll
      for (int ct = 0; ct < 4; ++ct) {
        const int m0 = mbase + wr * 64 + rt * 16 + l4 * 4;
        const int n = nloc + wc * 64 + ct * 16 + l15;
        #pragma unroll
        for (int j = 0; j < 4; ++j)
          O[(size_t)(m0 + j) * 512 + n] = f2h(acc[rt][ct][j]);
      }
  } else {
    // V transposed: Vt[b][d][t]; j runs over consecutive t -> 8B packed store
    #pragma unroll
    for (int rt = 0; rt < 4; ++rt)
      #pragma unroll
      for (int ct = 0; ct < 4; ++ct) {
        const int m0 = mbase + wr * 64 + rt * 16 + l4 * 4;
        const int d = nloc + wc * 64 + ct * 16 + l15;
        const int bb = m0 >> 11, t = m0 & 2047;
        unsigned long long pk = (unsigned long long)f2h(acc[rt][ct][0])
                              | ((unsigned long long)f2h(acc[rt][ct][1]) << 16)
                              | ((unsigned long long)f2h(acc[rt][ct][2]) << 32)
                              | ((unsigned long long)f2h(acc[rt][ct][3]) << 48);
        *(unsigned long long*)(Vtb + ((size_t)bb * 512 + d) * 2048 + t) = pk;
      }
  }
}

// ---------------------------------------------------------------- flash attention
// 256 WGs x 8 waves. WG = (batch, pair): q-tiles {pair, 63-pair} of 32 rows each
// -> every WG does exactly 65 KV-tile (32-row) iterations (causal balance).
// Wave w: QK^T role (sr=(w>>1)&1, sc=w&1, dh=w>>2: 16x16 S-tile, half of D),
//         PV role: owns d-columns [w*64, w*64+64) for all 32 q-rows.
// K LDS [32][512] f16, swizzle granule^(row&7); Vt LDS [512][32] f16,
// swizzle granule^((d>>1)&3). Both double-buffered (global_load_lds prefetch).
__device__ __forceinline__ void stage_kv(
    const unsigned short* __restrict__ Kb, const unsigned short* __restrict__ Vtb,
    char* smem, int buf, int b, int kvt, int wv, int lane) {
  char* kdst = smem + buf * 32768;
  char* vdst = smem + LDS_V_OFF + buf * 32768;
  const size_t krow0 = ((size_t)b * T_ + (size_t)kvt * 32) * 512;
  #pragma unroll
  for (int i = 0; i < 4; ++i) {
    const int r = wv * 4 + i;                       // K tile row (1024B = one wave-load)
    gload_lds16(Kb + krow0 + (size_t)r * 512 + ((lane ^ (r & 7)) * 8), kdst + r * 1024);
  }
  const int vsw = ((lane & 3) ^ ((lane >> 3) & 3)) * 8;   // = granule ^ ((d>>1)&3)
  #pragma unroll
  for (int i = 0; i < 4; ++i) {
    const int db = wv * 4 + i;                      // 16 d-rows per 1KB block
    const int d = db * 16 + (lane >> 2);
    gload_lds16(Vtb + ((size_t)b * 512 + d) * T_ + kvt * 32 + vsw, vdst + db * 1024);
  }
}

__global__ __launch_bounds__(512, 2) void flash_kernel(
    const unsigned short* __restrict__ Qb, const unsigned short* __restrict__ Kb,
    const unsigned short* __restrict__ Vtb, float* __restrict__ out) {
  extern __shared__ char smem[];
  float* Sp = (float*)(smem + LDS_SP_OFF);          // [2 dh][32][36] f32 partial scores
  unsigned short* Pb = (unsigned short*)(smem + LDS_P_OFF);  // [32][40] f16
  float* rowm = (float*)(smem + LDS_RM_OFF);
  float* rowl = (float*)(smem + LDS_RL_OFF);
  float* ralph = (float*)(smem + LDS_AL_OFF);

  const int tid = threadIdx.x, lane = tid & 63, wv = tid >> 6;
  const int sr = (wv >> 1) & 1, sc = wv & 1, dh = wv >> 2;
  const int l15 = lane & 15, l4 = lane >> 4;
  const int b = blockIdx.x >> 5;
  const int pair = blockIdx.x & 31;

  for (int pass = 0; pass < 2; ++pass) {
    const int qt = pass ? (63 - pair) : pair;       // q-tile index (32 rows)
    const int nkv = qt + 1;
    __syncthreads();                                // prior pass fully done
    if (tid < 32) { rowm[tid] = -1e30f; rowl[tid] = 0.f; }

    half8 qf[8];                                    // Q rows sr*16+l15, D-half dh
    {
      const unsigned short* qp =
          Qb + ((size_t)b * T_ + (size_t)qt * 32 + sr * 16 + l15) * 512 + dh * 256 + l4 * 8;
      #pragma unroll
      for (int ks = 0; ks < 8; ++ks) qf[ks] = *(const half8*)(qp + ks * 32);
    }
    f32x4 o[2][4];
    #pragma unroll
    for (int rt = 0; rt < 2; ++rt)
      #pragma unroll
      for (int ct = 0; ct < 4; ++ct) o[rt][ct] = (f32x4){0.f, 0.f, 0.f, 0.f};

    stage_kv(Kb, Vtb, smem, 0, b, 0, wv, lane);

    for (int kv = 0; kv < nkv; ++kv) {
      const int buf = kv & 1;
      __syncthreads();                              // staged KV ready; prev PV done
      if (kv + 1 < nkv) stage_kv(Kb, Vtb, smem, buf ^ 1, b, kv + 1, wv, lane);

      // ---- QK^T (partial over D-half dh) ----
      f32x4 s = (f32x4){0.f, 0.f, 0.f, 0.f};
      {
        const char* kb = smem + buf * 32768;
        const int krow = sc * 16 + l15;
        const int rsw = krow & 7;
        #pragma unroll
        for (int ks = 0; ks < 8; ++ks) {
          const int G = (dh * 32 + ks * 4 + l4) ^ rsw;
          half8 kf = *(const half8*)(kb + krow * 1024 + G * 16);
          s = __builtin_amdgcn_mfma_f32_16x16x32_f16(qf[ks], kf, s, 0, 0, 0);
        }
      }
      {
        float* sp = Sp + dh * 1152 + (sr * 16 + l4 * 4) * 36 + sc * 16 + l15;
        #pragma unroll
        for (int j = 0; j < 4; ++j) sp[j * 36] = s[j];
      }
      barrier_lgkm();

      // ---- online softmax: row = wv*4 + l4, 16 lanes/row, 2 cols/lane ----
      {
        const int rw = wv * 4 + l4;
        const int c0 = l15 * 2;
        const float* s0 = Sp + rw * 36 + c0;
        float v0 = (s0[0] + s0[1152]) * SCALE_;
        float v1 = (s0[1] + s0[1153]) * SCALE_;
        const int qg = qt * 32 + rw;
        const int kg = kv * 32 + c0;
        if (kg > qg) v0 = -1e30f;
        if (kg + 1 > qg) v1 = -1e30f;
        float mx = fmaxf(v0, v1);
        #pragma unroll
        for (int m = 1; m < 16; m <<= 1) mx = fmaxf(mx, __shfl_xor(mx, m, 64));
        const float mold = rowm[rw];
        const float mnew = fmaxf(mold, mx);
        const float al = __expf(mold - mnew);
        const float p0 = __expf(v0 - mnew);
        const float p1 = __expf(v1 - mnew);
        // round to fp16 FIRST, and accumulate l from the rounded values so the
        // normalizer matches the P actually fed to the PV MFMA.
        const unsigned short h0 = f2h(p0), h1 = f2h(p1);
        const float p0r = (float)*(const _Float16*)&h0;
        const float p1r = (float)*(const _Float16*)&h1;
        float ps = p0r + p1r;
        #pragma unroll
        for (int m = 1; m < 16; m <<= 1) ps += __shfl_xor(ps, m, 64);
        *(unsigned int*)(Pb + rw * 40 + c0) = (unsigned int)h0 | ((unsigned int)h1 << 16);
        if (l15 == 0) { rowm[rw] = mnew; rowl[rw] = al * rowl[rw] + ps; ralph[rw] = al; }
      }
      barrier_lgkm();

      // ---- rescale O, then PV ----
      {
        float af[2][4];
        #pragma unroll
        for (int rt = 0; rt < 2; ++rt)
          #pragma unroll
          for (int j = 0; j < 4; ++j) af[rt][j] = ralph[rt * 16 + l4 * 4 + j];
        #pragma unroll
        for (int rt = 0; rt < 2; ++rt)
          #pragma unroll
          for (int ct = 0; ct < 4; ++ct)
            #pragma unroll
            for (int j = 0; j < 4; ++j) o[rt][ct][j] *= af[rt][j];
        half8 pa[2];
        #pragma unroll
        for (int rt = 0; rt < 2; ++rt)
          pa[rt] = *(const half8*)((const char*)Pb + (rt * 16 + l15) * 80 + l4 * 16);
        const char* vb = smem + LDS_V_OFF + buf * 32768;
        #pragma unroll
        for (int ct = 0; ct < 4; ++ct) {
          const int d = wv * 64 + ct * 16 + l15;
          const int G = l4 ^ ((d >> 1) & 3);
          half8 vf = *(const half8*)(vb + d * 64 + G * 16);
          #pragma unroll
          for (int rt = 0; rt < 2; ++rt)
            o[rt][ct] = __builtin_amdgcn_mfma_f32_16x16x32_f16(pa[rt], vf, o[rt][ct], 0, 0, 0);
        }
      }
    }

    // ---- epilogue: out = O / l ----
    {
      float linv[2][4];
      #pragma unroll
      for (int rt = 0; rt < 2; ++rt)
        #pragma unroll
        for (int j = 0; j < 4; ++j) linv[rt][j] = 1.0f / rowl[rt * 16 + l4 * 4 + j];
      const size_t tb = (size_t)b * T_ + (size_t)qt * 32;
      #pragma unroll
      for (int rt = 0; rt < 2; ++rt)
        #pragma unroll
        for (int ct = 0; ct < 4; ++ct) {
          const int d = wv * 64 + ct * 16 + l15;
          #pragma unroll
          for (int j = 0; j < 4; ++j) {
            const int t = rt * 16 + l4 * 4 + j;
            out[(tb + t) * 512 + d] = o[rt][ct][j] * linv[rt][j];
          }
        }
    }
  }
}

// ---------------------------------------------------------------- launch
extern "C" void kernel_launch(void* const* d_in, const int* in_sizes, int n_in,
                              void* d_out, int out_size, void* d_ws, size_t ws_size,
                              hipStream_t stream) {
  (void)in_sizes; (void)n_in; (void)out_size; (void)ws_size;
  const float* x  = (const float*)d_in[0];
  const float* wq = (const float*)d_in[1];
  const float* wk = (const float*)d_in[2];
  const float* wv = (const float*)d_in[3];
  float* out = (float*)d_out;

  unsigned short* ws   = (unsigned short*)d_ws;
  unsigned short* xb   = ws;                                    // [16384][512]
  unsigned short* wcat = xb + (size_t)16384 * 512;              // [1536][512]
  unsigned short* Qb   = wcat + (size_t)1536 * 512;             // [16384][512]
  unsigned short* Kb   = Qb + (size_t)16384 * 512;              // [16384][512]
  unsigned short* Vtb  = Kb + (size_t)16384 * 512;              // [8][512][2048]
  // total ws use: 68.7 MB

  cast_kernel<<<8960, 256, 0, stream>>>(x, wq, wk, wv, xb, wcat);
  gemm_qkv<<<dim3(12, 128), 256, 0, stream>>>(xb, wcat, Qb, Kb, Vtb);
  hipFuncSetAttribute(reinterpret_cast<const void*>(flash_kernel),
                      hipFuncAttributeMaxDynamicSharedMemorySize, SMEM_BYTES);
  flash_kernel<<<256, 512, SMEM_BYTES, stream>>>(Qb, Kb, Vtb, out);
}